// Round 7
// baseline (741.721 us; speedup 1.0000x reference)
//
#include <hip/hip_runtime.h>
#include <hip/hip_bf16.h>
#include <cstdint>
#include <cstddef>

// ---------------------------------------------------------------------------
//   x:    [B=128, T=256, D=1024] fp32
//   Wk:   [1024, 512] per dir    Wr: [128, 512]    bias: [512]
//   xp[dir][t*128+b][512] = x[b,t,:] @ Wk + bias   (bf16, t-major, bias folded)
//   gemm: A staged fp32->bf16 in-kernel (conv_x deleted), B via async LDS,
//         double-buffered.
//   LSTM: 64 blocks x 512 thr, 4 seqs/block. Wave w owns dim-group
//   [16w,16w+16) for ALL FOUR gates (B-operand striping) -> z_i/f/g/o land in
//   the same lane's C-regs: activations are register-local, x folded via
//   MFMA C-init, ONE lite barrier per step, no z LDS round-trip.
// ---------------------------------------------------------------------------

typedef __attribute__((ext_vector_type(8))) short short8;
typedef __attribute__((ext_vector_type(4))) float f32x4;
typedef __attribute__((address_space(1))) unsigned int gas_uint;
typedef __attribute__((address_space(3))) unsigned int las_uint;

__device__ __forceinline__ unsigned short f2b(float f) {
    unsigned int u = __float_as_uint(f);
    u += 0x7FFFu + ((u >> 16) & 1u);          // RNE
    return (unsigned short)(u >> 16);
}
__device__ __forceinline__ float b2f(unsigned short u) {
    return __uint_as_float(((unsigned int)u) << 16);
}
__device__ __forceinline__ unsigned int pk2(float lo, float hi) {
    __hip_bfloat162 v = __float22bfloat162_rn(float2{lo, hi});
    return *(unsigned int*)&v;
}
__device__ __forceinline__ float sigmoidf_(float z) { return 1.0f / (1.0f + __expf(-z)); }
__device__ __forceinline__ float tanhf_(float z) {
    float e = __expf(2.0f * z);
    return 1.0f - 2.0f / (e + 1.0f);
}

// workgroup barrier WITHOUT the vmcnt(0) drain __syncthreads would emit
#define LITE_BARRIER() asm volatile("s_waitcnt lgkmcnt(0)\n\ts_barrier" ::: "memory")

// async global->LDS 16B
__device__ __forceinline__ void async_ld16(const unsigned short* g, unsigned short* l) {
    __builtin_amdgcn_global_load_lds(
        (gas_uint*)(uintptr_t)g,
        (las_uint*)(uintptr_t)(unsigned int)(uintptr_t)l,
        16, 0, 0);
}

// ---------------------------------------------------------------------------
// Kernel 1: transpose + convert Wk [1024][512] -> Wk_t [512][1024] bf16
// ---------------------------------------------------------------------------
__global__ void conv_wk(const float* __restrict__ wf, const float* __restrict__ wb,
                        unsigned short* __restrict__ wt) {
    int dir = blockIdx.y;
    const float* w = dir ? wb : wf;
    int id = blockIdx.x * blockDim.x + threadIdx.x;
    int g = id >> 10, d = id & 1023;
    wt[(size_t)dir * 524288 + id] = f2b(w[d * 512 + g]);
}

// ---------------------------------------------------------------------------
// Kernel 2: GEMM xp = x(fp32->bf16)[32768,1024] @ Wk_t^T + bias -> bf16 t-major
// 128x128 tile, BK=64; A: fp32 VGPR staging + in-kernel cvt; B: async LDS.
// Double-buffered; XOR swizzle chunk^(row&7) on both A and B.
// ---------------------------------------------------------------------------
#define STAGE_B(KT, BS)                                                     \
    {                                                                       \
        _Pragma("unroll")                                                   \
        for (int c = 0; c < 4; ++c)                                         \
            async_ld16(gb[c] + (KT) * 64, (BS) + lbB[c]);                   \
    }

#define LOAD_A(KT)                                                          \
    {                                                                       \
        _Pragma("unroll")                                                   \
        for (int c = 0; c < 4; ++c) {                                       \
            av[c][0] = *(const float4*)(gx[c] + (KT) * 64);                 \
            av[c][1] = *(const float4*)(gx[c] + (KT) * 64 + 4);             \
        }                                                                   \
    }

#define WRITE_A(AS)                                                         \
    {                                                                       \
        _Pragma("unroll")                                                   \
        for (int c = 0; c < 4; ++c) {                                       \
            uint4 s;                                                        \
            s.x = pk2(av[c][0].x, av[c][0].y);                              \
            s.y = pk2(av[c][0].z, av[c][0].w);                              \
            s.z = pk2(av[c][1].x, av[c][1].y);                              \
            s.w = pk2(av[c][1].z, av[c][1].w);                              \
            *(uint4*)((AS) + lwA[c]) = s;                                   \
        }                                                                   \
    }

#define GEMM_COMPUTE(AS, BS)                                                \
    {                                                                       \
        _Pragma("unroll")                                                   \
        for (int ks = 0; ks < 2; ++ks) {                                    \
            short8 af[4], bfr[4];                                           \
            _Pragma("unroll")                                               \
            for (int i = 0; i < 4; ++i) {                                   \
                int row = wm * 64 + i * 16 + lanelo;                        \
                af[i] = *(const short8*)((AS) + row * 64 +                  \
                         (((ks * 4 + quad) ^ (row & 7)) * 8));              \
            }                                                               \
            _Pragma("unroll")                                               \
            for (int j = 0; j < 4; ++j) {                                   \
                int row = wn * 64 + j * 16 + lanelo;                        \
                bfr[j] = *(const short8*)((BS) + row * 64 +                 \
                         (((ks * 4 + quad) ^ (row & 7)) * 8));              \
            }                                                               \
            _Pragma("unroll")                                               \
            for (int i = 0; i < 4; ++i)                                     \
                _Pragma("unroll")                                           \
                for (int j = 0; j < 4; ++j)                                 \
                    acc[i][j] = __builtin_amdgcn_mfma_f32_16x16x32_bf16(    \
                        af[i], bfr[j], acc[i][j], 0, 0, 0);                 \
        }                                                                   \
    }

__global__ __launch_bounds__(256, 2) void gemm_xp(
    const float* __restrict__ X,             // [32768][1024] fp32
    const unsigned short* __restrict__ Wt,   // [2][512][1024] bf16
    const float* __restrict__ bf_, const float* __restrict__ bb_,
    unsigned short* __restrict__ XP)
{
    __shared__ unsigned short As0[128 * 64];
    __shared__ unsigned short As1[128 * 64];
    __shared__ unsigned short Bs0[128 * 64];
    __shared__ unsigned short Bs1[128 * 64];

    const int tid  = threadIdx.x;
    const int tn   = blockIdx.x & 3;         // 0..3
    const int dir  = blockIdx.x >> 2;        // 0..1
    const int tm   = blockIdx.y;             // 0..255
    const int w    = tid >> 6;
    const int lane = tid & 63;
    const int lanelo = lane & 15;
    const int quad = lane >> 4;
    const int wm = w & 1, wn = w >> 1;

    const unsigned short* Bmat = Wt + (size_t)dir * 524288;
    const float* bias = dir ? bb_ : bf_;
    unsigned short* out = XP + (size_t)dir * 16777216;

    const float* gx[4];
    const unsigned short* gb[4];
    int lwA[4], lbB[4];
#pragma unroll
    for (int c = 0; c < 4; ++c) {
        int p = c * 256 + tid;
        int row = p >> 3;
        int lc = (p & 7) ^ (row & 7);
        gx[c] = X    + (size_t)(tm * 128 + row) * 1024 + lc * 8;
        gb[c] = Bmat + (size_t)(tn * 128 + row) * 1024 + lc * 8;
        lwA[c] = p * 8;                            // chunk p -> elems [p*8, p*8+8)
        lbB[c] = (c * 256 + (tid & ~63)) * 8;      // wave-uniform async base
    }

    float4 av[4][2];
    f32x4 acc[4][4];
#pragma unroll
    for (int i = 0; i < 4; i++)
#pragma unroll
        for (int j = 0; j < 4; j++) acc[i][j] = (f32x4){0.f, 0.f, 0.f, 0.f};

    LOAD_A(0); STAGE_B(0, Bs0); WRITE_A(As0);

#pragma unroll 1
    for (int kt2 = 0; kt2 < 16; kt2 += 2) {
        __syncthreads();                     // buf0(kt2) ready (A writes + B async)
        if (kt2 + 1 < 16) { LOAD_A(kt2 + 1); STAGE_B(kt2 + 1, Bs1); }
        GEMM_COMPUTE(As0, Bs0);
        if (kt2 + 1 < 16) WRITE_A(As1);

        __syncthreads();                     // buf1(kt2+1) ready
        if (kt2 + 2 < 16) { LOAD_A(kt2 + 2); STAGE_B(kt2 + 2, Bs0); }
        GEMM_COMPUTE(As1, Bs1);
        if (kt2 + 2 < 16) WRITE_A(As0);
    }

    float biasv[4];
#pragma unroll
    for (int j = 0; j < 4; ++j)
        biasv[j] = bias[tn * 128 + wn * 64 + j * 16 + lanelo];

#pragma unroll
    for (int i = 0; i < 4; ++i) {
#pragma unroll
        for (int r = 0; r < 4; ++r) {
            int gr = tm * 128 + wm * 64 + i * 16 + quad * 4 + r;   // = b*256 + t
            int bb = gr >> 8, tt = gr & 255;
            size_t orow = (size_t)(tt * 128 + bb) * 512;
#pragma unroll
            for (int j = 0; j < 4; ++j) {
                int col = tn * 128 + wn * 64 + j * 16 + lanelo;
                out[orow + col] = f2b(acc[i][j][r] + biasv[j]);
            }
        }
    }
}

// ---------------------------------------------------------------------------
// Kernel 3: LSTM recurrence. 64 blocks x 512 thr; block = (dir, 4 seqs).
// A = h (m=seq), B = Wr cols; wave w owns dims [16w,16w+16) x 4 gates.
// z_i/f/g/o co-located in C-regs of quad0 lanes -> register activations,
// x via MFMA C-init, one lite barrier/step.
// ---------------------------------------------------------------------------
#define LSTM_STEP(CUR, T, XARR)                                              \
    {                                                                        \
        short8 ha[4];                                                        \
        _Pragma("unroll")                                                    \
        for (int ks = 0; ks < 4; ++ks)                                       \
            ha[ks] = *(const short8*)(&h_lds[CUR][lanelo & 3][ks * 32 + quad * 8]); \
        f32x4 z[4];                                                          \
        _Pragma("unroll")                                                    \
        for (int G = 0; G < 4; ++G) {                                        \
            f32x4 a;                                                         \
            _Pragma("unroll")                                                \
            for (int r = 0; r < 4; ++r)                                      \
                a[r] = b2f((unsigned short)XARR[r][G]);                      \
            _Pragma("unroll")                                                \
            for (int ks = 0; ks < 4; ++ks)                                   \
                a = __builtin_amdgcn_mfma_f32_16x16x32_bf16(ha[ks], wrf[G][ks], a, 0, 0, 0); \
            z[G] = a;                                                        \
        }                                                                    \
        {                                                                    \
            const unsigned short* rn = rowp((T) + 2);                        \
            _Pragma("unroll")                                                \
            for (int r = 0; r < 4; ++r)                                      \
                _Pragma("unroll")                                            \
                for (int G = 0; G < 4; ++G)                                  \
                    XARR[r][G] = rn[vx[r][G]];                               \
        }                                                                    \
        _Pragma("unroll")                                                    \
        for (int r = 0; r < 4; ++r) {                                        \
            float iv = sigmoidf_(z[0][r]);                                   \
            float fv = sigmoidf_(z[1][r]);                                   \
            float gv = tanhf_(z[2][r]);                                      \
            float ov = sigmoidf_(z[3][r]);                                   \
            cv[r] = fv * cv[r] + iv * gv;                                    \
            hv[r] = ov * tanhf_(cv[r]);                                      \
        }                                                                    \
        if (quad == 0) {                                                     \
            _Pragma("unroll")                                                \
            for (int r = 0; r < 4; ++r)                                      \
                h_lds[(CUR) ^ 1][r][16 * w + lanelo] = f2b(hv[r]);           \
        }                                                                    \
        LITE_BARRIER();                                                      \
    }

__global__ __launch_bounds__(512, 2) void lstm_rec(
    const unsigned short* __restrict__ XP,    // [2][256*128][512] bf16, bias folded
    const float* __restrict__ Wfr, const float* __restrict__ Wbr,
    float* __restrict__ Hout)                 // [2][128][128]
{
    __shared__ unsigned short h_lds[2][4][144]; // [buf][seq][dim], 288B rows

    const int tid    = threadIdx.x;
    const int w      = tid >> 6;              // 0..7
    const int lane   = tid & 63;
    const int lanelo = lane & 15;
    const int quad   = lane >> 4;
    const int dir    = blockIdx.x >> 5;
    const int b0     = (blockIdx.x & 31) * 4;

    const float* Wr = dir ? Wbr : Wfr;
    const unsigned short* xp = XP + (size_t)dir * 16777216;

    // --- one-time: Wr B-frags. wave w, gate G -> cols 128G + 16w + lanelo ---
    short8 wrf[4][4];
#pragma unroll
    for (int G = 0; G < 4; ++G) {
        int col = 128 * G + 16 * w + lanelo;
#pragma unroll
        for (int ks = 0; ks < 4; ++ks) {
            short8 f;
#pragma unroll
            for (int j = 0; j < 8; ++j)
                f[j] = (short)f2b(Wr[(ks * 32 + quad * 8 + j) * 512 + col]);
            wrf[G][ks] = f;
        }
    }

    // x lane offsets: seq r, gate G (quad-independent -> broadcast loads)
    int vx[4][4];
#pragma unroll
    for (int r = 0; r < 4; ++r)
#pragma unroll
        for (int G = 0; G < 4; ++G)
            vx[r][G] = (b0 + r) * 512 + 128 * G + 16 * w + lanelo;

    for (int i = tid; i < 4 * 144; i += 512) ((unsigned short*)h_lds[0])[i] = 0;

    auto rowp = [&](int t) {
        int tc = t > 255 ? 255 : t;
        int rt = dir ? (255 - tc) : tc;
        return xp + (size_t)rt * 65536;
    };

    unsigned int xA[4][4], xB[4][4];
    {
        const unsigned short* r0 = rowp(0);
        const unsigned short* r1 = rowp(1);
#pragma unroll
        for (int r = 0; r < 4; ++r)
#pragma unroll
            for (int G = 0; G < 4; ++G) {
                xA[r][G] = r0[vx[r][G]];
                xB[r][G] = r1[vx[r][G]];
            }
    }

    f32x4 cv = (f32x4){0.f, 0.f, 0.f, 0.f};
    f32x4 hv = (f32x4){0.f, 0.f, 0.f, 0.f};

    LITE_BARRIER();                           // h_lds[0] zeros visible

#pragma unroll 1
    for (int tt = 0; tt < 256; tt += 2) {
        LSTM_STEP(0, tt, xA);
        LSTM_STEP(1, tt + 1, xB);
    }

    if (quad == 0) {
#pragma unroll
        for (int r = 0; r < 4; ++r)
            Hout[(size_t)(dir * 128 + b0 + r) * 128 + 16 * w + lanelo] = hv[r];
    }
}

// ---------------------------------------------------------------------------
// Kernel 4: MLP head
// ---------------------------------------------------------------------------
__global__ void mlp_head(const float* __restrict__ Hout,
                         const float* __restrict__ W1, const float* __restrict__ b1,
                         const float* __restrict__ W2, const float* __restrict__ b2,
                         float* __restrict__ out)
{
    __shared__ float y1[32];
    int b = blockIdx.x;
    int j = threadIdx.x;
    const float* hf = Hout + (size_t)b * 128;
    const float* hb = Hout + (size_t)(128 + b) * 128;
    if (j < 32) {
        float acc = b1[j];
        for (int k = 0; k < 128; ++k) acc += hf[k] * W1[k * 32 + j];
        for (int k = 0; k < 128; ++k) acc += hb[k] * W1[(128 + k) * 32 + j];
        y1[j] = fmaxf(acc, 0.0f);
    }
    __syncthreads();
    if (j < 2) {
        float z = b2[j];
        for (int k = 0; k < 32; ++k) z += y1[k] * W2[k * 2 + j];
        out[b * 2 + j] = 1.0f / (1.0f + __expf(-z));
    }
}

// ---------------------------------------------------------------------------
extern "C" void kernel_launch(void* const* d_in, const int* in_sizes, int n_in,
                              void* d_out, int out_size, void* d_ws, size_t ws_size,
                              hipStream_t stream) {
    const float* x    = (const float*)d_in[0];
    const float* Wf_k = (const float*)d_in[1];
    const float* Wf_r = (const float*)d_in[2];
    const float* bf   = (const float*)d_in[3];
    const float* Wb_k = (const float*)d_in[4];
    const float* Wb_r = (const float*)d_in[5];
    const float* bb   = (const float*)d_in[6];
    const float* W1   = (const float*)d_in[7];
    const float* b1   = (const float*)d_in[8];
    const float* W2   = (const float*)d_in[9];
    const float* b2   = (const float*)d_in[10];
    float* out = (float*)d_out;

    char* ws = (char*)d_ws;
    const size_t OFF_WT   = 0;                        //  2,097,152 B
    const size_t OFF_HOUT = 2097152;                  //    131,072 B
    const size_t OFF_XP   = OFF_HOUT + 131072;        // 67,108,864 B (bf16)

    unsigned short* wt = (unsigned short*)(ws + OFF_WT);
    float*          ho = (float*)(ws + OFF_HOUT);
    unsigned short* xp = (unsigned short*)(ws + OFF_XP);

    conv_wk<<<dim3(2048, 2), dim3(256), 0, stream>>>(Wf_k, Wb_k, wt);
    gemm_xp<<<dim3(8, 256), dim3(256), 0, stream>>>(x, wt, bf, bb, xp);
    lstm_rec<<<dim3(64), dim3(512), 0, stream>>>(xp, Wf_r, Wb_r, ho);
    mlp_head<<<dim3(128), dim3(64), 0, stream>>>(ho, W1, b1, W2, b2, out);
}